// Round 10
// baseline (697.282 us; speedup 1.0000x reference)
//
#include <hip/hip_runtime.h>
#include <hip/hip_cooperative_groups.h>

namespace cg = cooperative_groups;

typedef __bf16 bf16x8 __attribute__((ext_vector_type(8)));
typedef float  f32x4  __attribute__((ext_vector_type(4)));
typedef float  f32x8  __attribute__((ext_vector_type(8)));
typedef unsigned short ushort;
typedef ushort us8 __attribute__((ext_vector_type(8)));

constexpr int N_NODES = 50000;
constexpr int N_EDGES = 800000;
constexpr int SLOTS = 64;                     // bucket capacity (mean deg 16, Poisson tail << 64)
constexpr int GE   = N_EDGES / 256;           // 3125 (exact)
constexpr int WBLK = (3 * 9216) / 256;        // 108 (exact)
constexpr int GMF  = (N_NODES + 63) / 64;     // 782 gemm tiles
constexpr int GAGG = N_NODES / 16;            // 3125 agg tiles (exact)

__device__ inline float h16f(ushort u) {
    union { _Float16 h; ushort u; } cv; cv.u = u; return (float)cv.h;
}
__device__ inline ushort f16b(float f) {
    union { _Float16 h; ushort u; } cv; cv.h = (_Float16)f; return cv.u;
}
__device__ inline ushort bf16b(float f) {
    union { __bf16 b; ushort u; } cv; cv.b = (__bf16)f; return cv.u;
}
__device__ inline f32x8 bf8_to_f32(us8 u) {
    f32x8 r;
#pragma unroll
    for (int i = 0; i < 8; ++i) r[i] = __uint_as_float(((unsigned int)u[i]) << 16);
    return r;
}

// ---------------- gemm tile: 64 rows x 96 cols, MFMA 16x16x32 ----------------
template<int IN>   // 0: fp32 row-major in, 1: bf16 row-major in
__device__ __forceinline__ void gemm_tile(ushort* sS, const void* Xv,
                                          const ushort* __restrict__ Wt,
                                          ushort* __restrict__ Y, int bt) {
    ushort* sX = sS;            // 64*96 ushorts, 12 KB
    ushort* sW = sS + 64 * 96;  // 96*96 ushorts, 18 KB, [c][k]
    const int tid = threadIdx.x;
    const int rowbase = bt * 64;

    __syncthreads();   // protect LDS from previous use
    for (int i = tid; i < 9216 / 8; i += 256)
        ((uint4*)sW)[i] = ((const uint4*)Wt)[i];

    if (IN == 0) {
        const float* X = (const float*)Xv;
        for (int i = tid; i < 64 * 24; i += 256) {
            int r = i / 24, c4 = i % 24;
            int gr = rowbase + r;
            float4 v = make_float4(0.f, 0.f, 0.f, 0.f);
            if (gr < N_NODES) v = ((const float4*)(X + (size_t)gr * 96))[c4];
            ushort* p = sX + r * 96 + c4 * 4;
            p[0] = bf16b(v.x); p[1] = bf16b(v.y); p[2] = bf16b(v.z); p[3] = bf16b(v.w);
        }
    } else {
        const ushort* X = (const ushort*)Xv;
        for (int i = tid; i < 64 * 12; i += 256) {
            int r = i / 12, c8 = i % 12;
            int gr = rowbase + r;
            uint4 v = make_uint4(0, 0, 0, 0);
            if (gr < N_NODES) v = ((const uint4*)(X + (size_t)gr * 96))[c8];
            ((uint4*)(sX + r * 96))[c8] = v;
        }
    }
    __syncthreads();

    const int wv = tid >> 6, lane = tid & 63, quad = lane >> 4, l16 = lane & 15;
    f32x4 acc[6];
#pragma unroll
    for (int t = 0; t < 6; ++t) acc[t] = (f32x4){0.f, 0.f, 0.f, 0.f};

    const ushort* ax = sX + (wv * 16 + l16) * 96 + quad * 8;
#pragma unroll
    for (int s = 0; s < 3; ++s) {
        bf16x8 a = *(const bf16x8*)(ax + s * 32);
#pragma unroll
        for (int t = 0; t < 6; ++t) {
            bf16x8 b = *(const bf16x8*)(sW + (t * 16 + l16) * 96 + s * 32 + quad * 8);
            acc[t] = __builtin_amdgcn_mfma_f32_16x16x32_bf16(a, b, acc[t], 0, 0, 0);
        }
    }
    // C/D layout: col = lane&15, row = quad*4 + reg
    const int r0 = rowbase + wv * 16 + quad * 4;
#pragma unroll
    for (int t = 0; t < 6; ++t) {
#pragma unroll
        for (int g = 0; g < 4; ++g) {
            int r = r0 + g;
            if (r < N_NODES) Y[(size_t)r * 96 + t * 16 + l16] = bf16b(acc[t][g]);
        }
    }
}

// ---------------- gather+norm+bias+relu for one (node, chunk) ----------------
__device__ __forceinline__ f32x8 agg_gather(const ushort* __restrict__ A,
                                            const int* __restrict__ cnt,
                                            const unsigned int* __restrict__ csr,
                                            const float* __restrict__ bias,
                                            int n, int c) {
    const int deg = cnt[n];
    const float dn = rsqrtf((float)(deg + 1));
    f32x8 acc = bf8_to_f32(*(const us8*)(A + (size_t)n * 96 + c * 8)) * (dn * dn);

    const unsigned int* row = csr + (size_t)n * SLOTS;
    int j = 0;
    for (; j + 4 <= deg; j += 4) {
        const uint4 q = *(const uint4*)(row + j);       // broadcast across 12 chunk-threads
        const us8 u0 = *(const us8*)(A + (size_t)(q.x & 0xFFFFu) * 96 + c * 8);
        const us8 u1 = *(const us8*)(A + (size_t)(q.y & 0xFFFFu) * 96 + c * 8);
        const us8 u2 = *(const us8*)(A + (size_t)(q.z & 0xFFFFu) * 96 + c * 8);
        const us8 u3 = *(const us8*)(A + (size_t)(q.w & 0xFFFFu) * 96 + c * 8);
        acc += bf8_to_f32(u0) * (h16f((ushort)(q.x >> 16)) * dn);
        acc += bf8_to_f32(u1) * (h16f((ushort)(q.y >> 16)) * dn);
        acc += bf8_to_f32(u2) * (h16f((ushort)(q.z >> 16)) * dn);
        acc += bf8_to_f32(u3) * (h16f((ushort)(q.w >> 16)) * dn);
    }
    for (; j < deg; ++j) {
        const unsigned int e = row[j];
        const float w = h16f((ushort)(e >> 16)) * dn;
        const us8 u = *(const us8*)(A + (size_t)(e & 0xFFFFu) * 96 + c * 8);
        acc += bf8_to_f32(u) * w;
    }
#pragma unroll
    for (int f = 0; f < 8; ++f) acc[f] = fmaxf(acc[f] + bias[c * 8 + f], 0.0f);
    return acc;
}

// ---------------- the mega kernel ----------------
__global__ __launch_bounds__(256, 4) void k_mega(
    const float* __restrict__ x, const int* __restrict__ src, const int* __restrict__ dst,
    const float* __restrict__ W0, const float* __restrict__ W1, const float* __restrict__ W2,
    const float* __restrict__ b0, const float* __restrict__ b1, const float* __restrict__ b2,
    const float* __restrict__ Wfc, const float* __restrict__ bfc,
    int* __restrict__ cnt, ushort* __restrict__ rank, unsigned int* __restrict__ csr,
    ushort* __restrict__ Wt, ushort* __restrict__ H, ushort* __restrict__ G,
    float* __restrict__ out) {
    cg::grid_group grid = cg::this_grid();
    __shared__ ushort sS[64 * 96 + 96 * 96];   // 30 KB, aliased per phase
    const int tid = threadIdx.x;
    const int GS = gridDim.x;

    // ---- P0: zero cnt ----
    for (int i = blockIdx.x * 256 + tid; i < N_NODES; i += GS * 256) cnt[i] = 0;
    grid.sync();

    // ---- P1: count(+rank)  ||  W-prep ----
    for (int vb = blockIdx.x; vb < GE + WBLK; vb += GS) {
        if (vb < GE) {
            int e = vb * 256 + tid;
            rank[e] = (ushort)atomicAdd(&cnt[dst[e]], 1);
        } else {
            int i = (vb - GE) * 256 + tid;    // exact: WBLK*256 == 3*9216
            int m = i / 9216, li = i - m * 9216;
            const float* W = (m == 0) ? W0 : (m == 1) ? W1 : W2;
            int k = li / 96, c = li - k * 96;
            Wt[m * 9216 + c * 96 + k] = bf16b(W[li]);
        }
    }
    grid.sync();

    // ---- P2: fill (atomic-free)  ||  gemm layer 1 ----
    for (int vb = blockIdx.x; vb < GE + GMF; vb += GS) {
        if (vb < GE) {
            int e = vb * 256 + tid;
            int s = src[e], d = dst[e];
            float hs = rsqrtf((float)(cnt[s] + 1));
            unsigned int entry = (unsigned int)(ushort)s | ((unsigned int)f16b(hs) << 16);
            csr[(size_t)d * SLOTS + rank[e]] = entry;
        } else {
            gemm_tile<0>(sS, (const void*)x, Wt, H, vb - GE);
        }
    }
    grid.sync();

    // ---- P3: agg layer 1 (H -> G bf16) ----
    for (int vb = blockIdx.x; vb < GAGG; vb += GS) {
        if (tid < 192) {
            int g = tid / 12, c = tid % 12;
            int n = vb * 16 + g;
            f32x8 acc = agg_gather(H, cnt, csr, b0, n, c);
            us8 o;
#pragma unroll
            for (int f = 0; f < 8; ++f) o[f] = bf16b(acc[f]);
            *(us8*)(G + (size_t)n * 96 + c * 8) = o;
        }
    }
    grid.sync();

    // ---- P4: gemm layer 2 (G -> H) ----
    for (int vb = blockIdx.x; vb < GMF; vb += GS)
        gemm_tile<1>(sS, (const void*)G, Wt + 9216, H, vb);
    grid.sync();

    // ---- P5: agg layer 2 (H -> G) ----
    for (int vb = blockIdx.x; vb < GAGG; vb += GS) {
        if (tid < 192) {
            int g = tid / 12, c = tid % 12;
            int n = vb * 16 + g;
            f32x8 acc = agg_gather(H, cnt, csr, b1, n, c);
            us8 o;
#pragma unroll
            for (int f = 0; f < 8; ++f) o[f] = bf16b(acc[f]);
            *(us8*)(G + (size_t)n * 96 + c * 8) = o;
        }
    }
    grid.sync();

    // ---- P6: gemm layer 3 (G -> H) ----
    for (int vb = blockIdx.x; vb < GMF; vb += GS)
        gemm_tile<1>(sS, (const void*)G, Wt + 2 * 9216, H, vb);
    grid.sync();

    // ---- P7: agg layer 3 + fused fc (H -> out) ----
    {
        float* sWfc = (float*)sS;          // 384 floats
        float* red  = (float*)sS + 384;    // 16*12*4 = 768 floats
        __syncthreads();                    // LDS free of P6 use
        for (int i = tid; i < 384; i += 256) sWfc[i] = Wfc[i];
        __syncthreads();
        for (int vb = blockIdx.x; vb < GAGG; vb += GS) {
            if (tid < 192) {
                int g = tid / 12, c = tid % 12;
                int n = vb * 16 + g;
                f32x8 acc = agg_gather(H, cnt, csr, b2, n, c);
                float p0 = 0.f, p1 = 0.f, p2 = 0.f, p3 = 0.f;
#pragma unroll
                for (int f = 0; f < 8; ++f) {
                    const float* wr = sWfc + (c * 8 + f) * 4;
                    p0 += acc[f] * wr[0];
                    p1 += acc[f] * wr[1];
                    p2 += acc[f] * wr[2];
                    p3 += acc[f] * wr[3];
                }
                float* rr = red + (g * 12 + c) * 4;
                rr[0] = p0; rr[1] = p1; rr[2] = p2; rr[3] = p3;
            }
            __syncthreads();
            if (tid < 64) {
                int gg = tid >> 2, jj = tid & 3;
                float s = bfc[jj];
#pragma unroll
                for (int cc = 0; cc < 12; ++cc) s += red[(gg * 12 + cc) * 4 + jj];
                out[(size_t)(vb * 16 + gg) * 4 + jj] = s;
            }
            __syncthreads();
        }
    }
}

// ---------------- launch ----------------
extern "C" void kernel_launch(void* const* d_in, const int* in_sizes, int n_in,
                              void* d_out, int out_size, void* d_ws, size_t ws_size,
                              hipStream_t stream) {
    const float* x   = (const float*)d_in[0];
    const int*   ei  = (const int*)d_in[1];
    const int*   src = ei;
    const int*   dst = ei + N_EDGES;
    const float* W0  = (const float*)d_in[2];
    const float* b0  = (const float*)d_in[3];
    const float* W1  = (const float*)d_in[4];
    const float* b1  = (const float*)d_in[5];
    const float* W2  = (const float*)d_in[6];
    const float* b2  = (const float*)d_in[7];
    const float* Wfc = (const float*)d_in[8];
    const float* bfc = (const float*)d_in[9];
    float* out = (float*)d_out;

    // workspace layout (16 B-aligned blocks)
    char* w = (char*)d_ws;
    unsigned int* csr = (unsigned int*)w;  w += ((size_t)N_NODES * SLOTS * 4 + 15) & ~15ULL;
    int*    cnt  = (int*)w;                w += ((size_t)N_NODES * 4 + 15) & ~15ULL;
    ushort* rank = (ushort*)w;             w += ((size_t)N_EDGES * 2 + 15) & ~15ULL;
    ushort* Wt   = (ushort*)w;             w += ((size_t)3 * 9216 * 2 + 15) & ~15ULL;
    ushort* H    = (ushort*)w;             w += ((size_t)N_NODES * 96 * 2 + 15) & ~15ULL;
    ushort* G    = (ushort*)w;             // N_NODES * 96 bf16

    // grid: target 4 blocks/CU, clamped by what the driver will co-schedule
    int perCU = 0;
    hipOccupancyMaxActiveBlocksPerMultiprocessor(&perCU, (const void*)k_mega, 256, 0);
    if (perCU < 1) perCU = 1;
    if (perCU > 4) perCU = 4;
    int grid = perCU * 256;

    void* args[] = {
        (void*)&x, (void*)&src, (void*)&dst,
        (void*)&W0, (void*)&W1, (void*)&W2,
        (void*)&b0, (void*)&b1, (void*)&b2,
        (void*)&Wfc, (void*)&bfc,
        (void*)&cnt, (void*)&rank, (void*)&csr,
        (void*)&Wt, (void*)&H, (void*)&G, (void*)&out
    };
    hipLaunchCooperativeKernel((void*)k_mega, dim3(grid), dim3(256), args, 0, stream);
}

// Round 11
// 239.715 us; speedup vs baseline: 2.9088x; 2.9088x over previous
//
#include <hip/hip_runtime.h>

typedef __bf16 bf16x8 __attribute__((ext_vector_type(8)));
typedef float  f32x4  __attribute__((ext_vector_type(4)));
typedef float  f32x8  __attribute__((ext_vector_type(8)));
typedef unsigned short ushort;
typedef ushort us8 __attribute__((ext_vector_type(8)));

constexpr int N_NODES = 50000;
constexpr int N_EDGES = 800000;
constexpr int SLOTS = 64;                     // bucket capacity (mean deg 16, Poisson tail << 64)
constexpr int GE   = N_EDGES / 256;           // 3125 (exact)
constexpr int WBLK = (3 * 9216) / 256;        // 108 (exact)
constexpr int GMF  = (N_NODES + 63) / 64;     // 782 gemm tiles

__device__ inline float h16f(ushort u) {
    union { _Float16 h; ushort u; } cv; cv.u = u; return (float)cv.h;
}
__device__ inline ushort f16b(float f) {
    union { _Float16 h; ushort u; } cv; cv.h = (_Float16)f; return cv.u;
}
__device__ inline ushort bf16b(float f) {
    union { __bf16 b; ushort u; } cv; cv.b = (__bf16)f; return cv.u;
}
__device__ inline f32x8 bf8_to_f32(us8 u) {
    f32x8 r;
#pragma unroll
    for (int i = 0; i < 8; ++i) r[i] = __uint_as_float(((unsigned int)u[i]) << 16);
    return r;
}

// ---------------- count (+rank) + W-prep ----------------
__global__ __launch_bounds__(256) void k_count(const int* __restrict__ dst,
                                               int* __restrict__ cnt,
                                               ushort* __restrict__ rank,
                                               const float* __restrict__ W0,
                                               const float* __restrict__ W1,
                                               const float* __restrict__ W2,
                                               ushort* __restrict__ Wt) {
    const int b = blockIdx.x;
    if (b < GE) {
        int e = b * 256 + threadIdx.x;
        rank[e] = (ushort)atomicAdd(&cnt[dst[e]], 1);
    } else {
        int i = (b - GE) * 256 + threadIdx.x;   // exact
        int m = i / 9216, li = i - m * 9216;
        const float* W = (m == 0) ? W0 : (m == 1) ? W1 : W2;
        int k = li / 96, c = li - k * 96;
        Wt[m * 9216 + c * 96 + k] = bf16b(W[li]);
    }
}

// ---------------- gemm tile body (64 rows x 96 cols, MFMA 16x16x32) ----------------
template<int IN>   // 0: fp32 row-major in, 1: bf16 row-major in
__device__ __forceinline__ void gemm_tile(ushort* sX, ushort* sW, const void* Xv,
                                          const ushort* __restrict__ Wt,
                                          ushort* __restrict__ Y, int bt) {
    const int tid = threadIdx.x;
    const int rowbase = bt * 64;

    for (int i = tid; i < 9216 / 8; i += 256)
        ((uint4*)sW)[i] = ((const uint4*)Wt)[i];

    if (IN == 0) {
        const float* X = (const float*)Xv;
        for (int i = tid; i < 64 * 24; i += 256) {
            int r = i / 24, c4 = i % 24;
            int gr = rowbase + r;
            float4 v = make_float4(0.f, 0.f, 0.f, 0.f);
            if (gr < N_NODES) v = ((const float4*)(X + (size_t)gr * 96))[c4];
            ushort* p = sX + r * 96 + c4 * 4;
            p[0] = bf16b(v.x); p[1] = bf16b(v.y); p[2] = bf16b(v.z); p[3] = bf16b(v.w);
        }
    } else {
        const ushort* X = (const ushort*)Xv;
        for (int i = tid; i < 64 * 12; i += 256) {
            int r = i / 12, c8 = i % 12;
            int gr = rowbase + r;
            uint4 v = make_uint4(0, 0, 0, 0);
            if (gr < N_NODES) v = ((const uint4*)(X + (size_t)gr * 96))[c8];
            ((uint4*)(sX + r * 96))[c8] = v;
        }
    }
    __syncthreads();

    const int wv = tid >> 6, lane = tid & 63, quad = lane >> 4, l16 = lane & 15;
    f32x4 acc[6];
#pragma unroll
    for (int t = 0; t < 6; ++t) acc[t] = (f32x4){0.f, 0.f, 0.f, 0.f};

    const ushort* ax = sX + (wv * 16 + l16) * 96 + quad * 8;
#pragma unroll
    for (int s = 0; s < 3; ++s) {
        bf16x8 a = *(const bf16x8*)(ax + s * 32);
#pragma unroll
        for (int t = 0; t < 6; ++t) {
            bf16x8 b = *(const bf16x8*)(sW + (t * 16 + l16) * 96 + s * 32 + quad * 8);
            acc[t] = __builtin_amdgcn_mfma_f32_16x16x32_bf16(a, b, acc[t], 0, 0, 0);
        }
    }
    // C/D layout: col = lane&15, row = quad*4 + reg
    const int r0 = rowbase + wv * 16 + quad * 4;
#pragma unroll
    for (int t = 0; t < 6; ++t) {
#pragma unroll
        for (int g = 0; g < 4; ++g) {
            int r = r0 + g;
            if (r < N_NODES) Y[(size_t)r * 96 + t * 16 + l16] = bf16b(acc[t][g]);
        }
    }
}

// ---------------- fused: fill (blocks [0,GE)) || gemm layer 1 (blocks [GE,GE+GMF)) ----------------
__global__ __launch_bounds__(256) void k_fill_gemm1(const int* __restrict__ src,
                                                    const int* __restrict__ dst,
                                                    const int* __restrict__ cnt,
                                                    const ushort* __restrict__ rank,
                                                    unsigned int* __restrict__ csr,
                                                    const float* __restrict__ x,
                                                    const ushort* __restrict__ Wt,
                                                    ushort* __restrict__ H) {
    __shared__ ushort sS[64 * 96 + 96 * 96];   // 30 KB (only gemm blocks use it)
    const int b = blockIdx.x;
    if (b < GE) {
        int e = b * 256 + threadIdx.x;   // GE*256 == N_EDGES, exact
        int s = src[e], d = dst[e];
        float hs = rsqrtf((float)(cnt[s] + 1));
        unsigned int entry = (unsigned int)(ushort)s | ((unsigned int)f16b(hs) << 16);
        csr[(size_t)d * SLOTS + rank[e]] = entry;
    } else {
        gemm_tile<0>(sS, sS + 64 * 96, (const void*)x, Wt, H, b - GE);
    }
}

// ---------------- standalone gemm (layers 2,3) ----------------
__global__ __launch_bounds__(256) void k_gemm_b(const ushort* __restrict__ X,
                                                const ushort* __restrict__ Wt,
                                                ushort* __restrict__ Y) {
    __shared__ ushort sS[64 * 96 + 96 * 96];
    gemm_tile<1>(sS, sS + 64 * 96, (const void*)X, Wt, Y, blockIdx.x);
}

// ---------------- fused aggregate over row-major bf16 H (bucket CSR, packed) ----------------
// 192 threads = 16 nodes x 12 chunks of 8 feats. N_NODES % 16 == 0 -> exact grid.
// MODE 0: out = bf16 H'   MODE 1: fused final fc -> out4
template<int MODE>
__global__ __launch_bounds__(192) void k_agg(const ushort* __restrict__ A,
                                             const int* __restrict__ cnt,
                                             const unsigned int* __restrict__ csr,
                                             const float* __restrict__ bias,
                                             ushort* __restrict__ Hout,
                                             float* __restrict__ out4,
                                             const float* __restrict__ Wfc,
                                             const float* __restrict__ bfc) {
    __shared__ float sWfc[384];
    __shared__ float red[16][12][4];
    const int tid = threadIdx.x;
    if (MODE == 1) {
        for (int i = tid; i < 384; i += 192) sWfc[i] = Wfc[i];
        __syncthreads();
    }
    const int g = tid / 12, c = tid % 12;
    const int n = blockIdx.x * 16 + g;

    const int deg = cnt[n];
    const float dn = rsqrtf((float)(deg + 1));
    us8 a0 = *(const us8*)(A + (size_t)n * 96 + c * 8);
    f32x8 acc = bf8_to_f32(a0) * (dn * dn);

    const unsigned int* row = csr + (size_t)n * SLOTS;
    int j = 0;
    for (; j + 4 <= deg; j += 4) {
        const uint4 q = *(const uint4*)(row + j);       // broadcast across 12 chunk-threads
        const us8 u0 = *(const us8*)(A + (size_t)(q.x & 0xFFFFu) * 96 + c * 8);
        const us8 u1 = *(const us8*)(A + (size_t)(q.y & 0xFFFFu) * 96 + c * 8);
        const us8 u2 = *(const us8*)(A + (size_t)(q.z & 0xFFFFu) * 96 + c * 8);
        const us8 u3 = *(const us8*)(A + (size_t)(q.w & 0xFFFFu) * 96 + c * 8);
        acc += bf8_to_f32(u0) * (h16f((ushort)(q.x >> 16)) * dn);
        acc += bf8_to_f32(u1) * (h16f((ushort)(q.y >> 16)) * dn);
        acc += bf8_to_f32(u2) * (h16f((ushort)(q.z >> 16)) * dn);
        acc += bf8_to_f32(u3) * (h16f((ushort)(q.w >> 16)) * dn);
    }
    for (; j < deg; ++j) {
        const unsigned int e = row[j];
        const float w = h16f((ushort)(e >> 16)) * dn;
        const us8 u = *(const us8*)(A + (size_t)(e & 0xFFFFu) * 96 + c * 8);
        acc += bf8_to_f32(u) * w;
    }
#pragma unroll
    for (int f = 0; f < 8; ++f) acc[f] = fmaxf(acc[f] + bias[c * 8 + f], 0.0f);

    if (MODE == 0) {
        us8 o;
#pragma unroll
        for (int f = 0; f < 8; ++f) o[f] = bf16b(acc[f]);
        *(us8*)(Hout + (size_t)n * 96 + c * 8) = o;
    } else {
        float p0 = 0.f, p1 = 0.f, p2 = 0.f, p3 = 0.f;
#pragma unroll
        for (int f = 0; f < 8; ++f) {
            const float* wr = sWfc + (c * 8 + f) * 4;
            p0 += acc[f] * wr[0];
            p1 += acc[f] * wr[1];
            p2 += acc[f] * wr[2];
            p3 += acc[f] * wr[3];
        }
        red[g][c][0] = p0; red[g][c][1] = p1; red[g][c][2] = p2; red[g][c][3] = p3;
        __syncthreads();
        if (tid < 64) {
            const int gg = tid >> 2, jj = tid & 3;
            float s = bfc[jj];
#pragma unroll
            for (int cc = 0; cc < 12; ++cc) s += red[gg][cc][jj];
            out4[(size_t)(blockIdx.x * 16 + gg) * 4 + jj] = s;
        }
    }
}

// ---------------- launch ----------------
extern "C" void kernel_launch(void* const* d_in, const int* in_sizes, int n_in,
                              void* d_out, int out_size, void* d_ws, size_t ws_size,
                              hipStream_t stream) {
    const float* x   = (const float*)d_in[0];
    const int*   ei  = (const int*)d_in[1];
    const int*   src = ei;
    const int*   dst = ei + N_EDGES;
    const float* W0  = (const float*)d_in[2];
    const float* b0  = (const float*)d_in[3];
    const float* W1  = (const float*)d_in[4];
    const float* b1  = (const float*)d_in[5];
    const float* W2  = (const float*)d_in[6];
    const float* b2  = (const float*)d_in[7];
    const float* Wfc = (const float*)d_in[8];
    const float* bfc = (const float*)d_in[9];
    float* out = (float*)d_out;

    // workspace layout (16 B-aligned blocks)
    char* w = (char*)d_ws;
    unsigned int* csr = (unsigned int*)w;  w += ((size_t)N_NODES * SLOTS * 4 + 15) & ~15ULL;
    int*    cnt  = (int*)w;                w += ((size_t)N_NODES * 4 + 15) & ~15ULL;
    ushort* rank = (ushort*)w;             w += ((size_t)N_EDGES * 2 + 15) & ~15ULL;
    ushort* Wt   = (ushort*)w;             w += ((size_t)3 * 9216 * 2 + 15) & ~15ULL;
    ushort* H    = (ushort*)w;             w += ((size_t)N_NODES * 96 * 2 + 15) & ~15ULL;
    ushort* G    = (ushort*)w;             // N_NODES * 96 bf16

    const int gAgg = N_NODES / 16;          // 3125, exact

    hipMemsetAsync(cnt, 0, (size_t)N_NODES * 4, stream);
    hipLaunchKernelGGL(k_count, dim3(GE + WBLK), dim3(256), 0, stream,
                       dst, cnt, rank, W0, W1, W2, Wt);
    // fill || gemm layer 1 (independent): one dispatch
    hipLaunchKernelGGL(k_fill_gemm1, dim3(GE + GMF), dim3(256), 0, stream,
                       src, dst, cnt, rank, csr, x, Wt, H);
    hipLaunchKernelGGL((k_agg<0>), dim3(gAgg), dim3(192), 0, stream,
                       H, cnt, csr, b0, G, (float*)nullptr,
                       (const float*)nullptr, (const float*)nullptr);
    // Layer 2
    hipLaunchKernelGGL(k_gemm_b, dim3(GMF), dim3(256), 0, stream, G, Wt + 9216, H);
    hipLaunchKernelGGL((k_agg<0>), dim3(gAgg), dim3(192), 0, stream,
                       H, cnt, csr, b1, G, (float*)nullptr,
                       (const float*)nullptr, (const float*)nullptr);
    // Layer 3 + fused fc
    hipLaunchKernelGGL(k_gemm_b, dim3(GMF), dim3(256), 0, stream, G, Wt + 2 * 9216, H);
    hipLaunchKernelGGL((k_agg<1>), dim3(gAgg), dim3(192), 0, stream,
                       H, cnt, csr, b2, (ushort*)nullptr, out, Wfc, bfc);
}

// Round 12
// 239.047 us; speedup vs baseline: 2.9169x; 1.0028x over previous
//
#include <hip/hip_runtime.h>

typedef __bf16 bf16x8 __attribute__((ext_vector_type(8)));
typedef float  f32x4  __attribute__((ext_vector_type(4)));
typedef float  f32x8  __attribute__((ext_vector_type(8)));
typedef unsigned short ushort;
typedef ushort us8 __attribute__((ext_vector_type(8)));

constexpr int N_NODES = 50000;
constexpr int N_EDGES = 800000;
constexpr int SLOTS = 64;                     // bucket capacity (mean deg 16, Poisson tail << 64)
constexpr int GE   = N_EDGES / 256;           // 3125 (exact)
constexpr int WBLK = (3 * 9216) / 256;        // 108 (exact)
constexpr int GMF  = (N_NODES + 63) / 64;     // 782 gemm tiles

__device__ inline float h16f(ushort u) {
    union { _Float16 h; ushort u; } cv; cv.u = u; return (float)cv.h;
}
__device__ inline ushort f16b(float f) {
    union { _Float16 h; ushort u; } cv; cv.h = (_Float16)f; return cv.u;
}
__device__ inline ushort bf16b(float f) {
    union { __bf16 b; ushort u; } cv; cv.b = (__bf16)f; return cv.u;
}
__device__ inline f32x8 bf8_to_f32(us8 u) {
    f32x8 r;
#pragma unroll
    for (int i = 0; i < 8; ++i) r[i] = __uint_as_float(((unsigned int)u[i]) << 16);
    return r;
}

// ---------------- count (+rank) + W-prep ----------------
__global__ __launch_bounds__(256) void k_count(const int* __restrict__ dst,
                                               int* __restrict__ cnt,
                                               ushort* __restrict__ rank,
                                               const float* __restrict__ W0,
                                               const float* __restrict__ W1,
                                               const float* __restrict__ W2,
                                               ushort* __restrict__ Wt) {
    const int b = blockIdx.x;
    if (b < GE) {
        int e = b * 256 + threadIdx.x;
        rank[e] = (ushort)atomicAdd(&cnt[dst[e]], 1);
    } else {
        int i = (b - GE) * 256 + threadIdx.x;   // exact
        int m = i / 9216, li = i - m * 9216;
        const float* W = (m == 0) ? W0 : (m == 1) ? W1 : W2;
        int k = li / 96, c = li - k * 96;
        Wt[m * 9216 + c * 96 + k] = bf16b(W[li]);
    }
}

// ---------------- MFMA part: sX[64x96] @ sW[96x96]^T-layout -> Y rows ----------------
__device__ __forceinline__ void mfma_store(const ushort* sX, const ushort* sW,
                                           ushort* __restrict__ Y, int rowbase) {
    const int tid = threadIdx.x;
    const int wv = tid >> 6, lane = tid & 63, quad = lane >> 4, l16 = lane & 15;
    f32x4 acc[6];
#pragma unroll
    for (int t = 0; t < 6; ++t) acc[t] = (f32x4){0.f, 0.f, 0.f, 0.f};

    const ushort* ax = sX + (wv * 16 + l16) * 96 + quad * 8;
#pragma unroll
    for (int s = 0; s < 3; ++s) {
        bf16x8 a = *(const bf16x8*)(ax + s * 32);
#pragma unroll
        for (int t = 0; t < 6; ++t) {
            bf16x8 b = *(const bf16x8*)(sW + (t * 16 + l16) * 96 + s * 32 + quad * 8);
            acc[t] = __builtin_amdgcn_mfma_f32_16x16x32_bf16(a, b, acc[t], 0, 0, 0);
        }
    }
    // C/D layout: col = lane&15, row = quad*4 + reg
    const int r0 = rowbase + wv * 16 + quad * 4;
#pragma unroll
    for (int t = 0; t < 6; ++t) {
#pragma unroll
        for (int g = 0; g < 4; ++g) {
            int r = r0 + g;
            if (r < N_NODES) Y[(size_t)r * 96 + t * 16 + l16] = bf16b(acc[t][g]);
        }
    }
}

// ---------------- fused: fill (blocks [0,GE)) || gemm layer 1 (blocks [GE,GE+GMF)) ----------------
__global__ __launch_bounds__(256) void k_fill_gemm1(const int* __restrict__ src,
                                                    const int* __restrict__ dst,
                                                    const int* __restrict__ cnt,
                                                    const ushort* __restrict__ rank,
                                                    unsigned int* __restrict__ csr,
                                                    const float* __restrict__ x,
                                                    const ushort* __restrict__ Wt,
                                                    ushort* __restrict__ H) {
    __shared__ ushort sS[64 * 96 + 96 * 96];   // 30 KB (only gemm blocks use it)
    const int b = blockIdx.x;
    const int tid = threadIdx.x;
    if (b < GE) {
        int e = b * 256 + tid;   // GE*256 == N_EDGES, exact
        int s = src[e], d = dst[e];
        float hs = rsqrtf((float)(cnt[s] + 1));
        unsigned int entry = (unsigned int)(ushort)s | ((unsigned int)f16b(hs) << 16);
        csr[(size_t)d * SLOTS + rank[e]] = entry;
    } else {
        ushort* sX = sS;
        ushort* sW = sS + 64 * 96;
        const int rowbase = (b - GE) * 64;
        for (int i = tid; i < 9216 / 8; i += 256)
            ((uint4*)sW)[i] = ((const uint4*)Wt)[i];
        for (int i = tid; i < 64 * 24; i += 256) {
            int r = i / 24, c4 = i % 24;
            int gr = rowbase + r;
            float4 v = make_float4(0.f, 0.f, 0.f, 0.f);
            if (gr < N_NODES) v = ((const float4*)(x + (size_t)gr * 96))[c4];
            ushort* p = sX + r * 96 + c4 * 4;
            p[0] = bf16b(v.x); p[1] = bf16b(v.y); p[2] = bf16b(v.z); p[3] = bf16b(v.w);
        }
        __syncthreads();
        mfma_store(sX, sW, H, rowbase);
    }
}

// ---------------- fused agg_l + gemm_{l+1}: gather H -> LDS -> MFMA -> Y ----------------
// agg phase: 256 threads = 64 nodes x 4 groups x 3 chunks of 8 feats (thread reads 48 B/row).
__global__ __launch_bounds__(256) void k_aggemm(const ushort* __restrict__ A,
                                                const int* __restrict__ cnt,
                                                const unsigned int* __restrict__ csr,
                                                const float* __restrict__ bias,
                                                const ushort* __restrict__ Wt,
                                                ushort* __restrict__ Y) {
    __shared__ ushort sS[64 * 96 + 96 * 96];   // 30 KB
    ushort* sX = sS;
    ushort* sW = sS + 64 * 96;
    const int tid = threadIdx.x;
    const int rowbase = blockIdx.x * 64;

    // W tile load first: independent of agg, overlaps its gather latency
    for (int i = tid; i < 9216 / 8; i += 256)
        ((uint4*)sW)[i] = ((const uint4*)Wt)[i];

    const int nl = tid >> 2;          // 0..63 local node
    const int grp = tid & 3;          // 0..3 -> chunks grp*3 .. grp*3+2
    const int n = rowbase + nl;
    if (n < N_NODES) {
        const int deg = cnt[n];
        const float dn = rsqrtf((float)(deg + 1));
        const float dn2 = dn * dn;
        const ushort* An = A + (size_t)n * 96 + grp * 24;
        f32x8 acc0 = bf8_to_f32(*(const us8*)(An))      * dn2;
        f32x8 acc1 = bf8_to_f32(*(const us8*)(An + 8))  * dn2;
        f32x8 acc2 = bf8_to_f32(*(const us8*)(An + 16)) * dn2;

        const unsigned int* row = csr + (size_t)n * SLOTS;
        int j = 0;
        for (; j + 4 <= deg; j += 4) {
            const uint4 q = *(const uint4*)(row + j);   // same addr across the node's 4 threads
            const ushort* p0 = A + (size_t)(q.x & 0xFFFFu) * 96 + grp * 24;
            const ushort* p1 = A + (size_t)(q.y & 0xFFFFu) * 96 + grp * 24;
            const ushort* p2 = A + (size_t)(q.z & 0xFFFFu) * 96 + grp * 24;
            const ushort* p3 = A + (size_t)(q.w & 0xFFFFu) * 96 + grp * 24;
            const us8 u00 = *(const us8*)p0, u01 = *(const us8*)(p0 + 8), u02 = *(const us8*)(p0 + 16);
            const us8 u10 = *(const us8*)p1, u11 = *(const us8*)(p1 + 8), u12 = *(const us8*)(p1 + 16);
            const us8 u20 = *(const us8*)p2, u21 = *(const us8*)(p2 + 8), u22 = *(const us8*)(p2 + 16);
            const us8 u30 = *(const us8*)p3, u31 = *(const us8*)(p3 + 8), u32 = *(const us8*)(p3 + 16);
            const float w0 = h16f((ushort)(q.x >> 16)) * dn;
            const float w1 = h16f((ushort)(q.y >> 16)) * dn;
            const float w2 = h16f((ushort)(q.z >> 16)) * dn;
            const float w3 = h16f((ushort)(q.w >> 16)) * dn;
            acc0 += bf8_to_f32(u00) * w0; acc1 += bf8_to_f32(u01) * w0; acc2 += bf8_to_f32(u02) * w0;
            acc0 += bf8_to_f32(u10) * w1; acc1 += bf8_to_f32(u11) * w1; acc2 += bf8_to_f32(u12) * w1;
            acc0 += bf8_to_f32(u20) * w2; acc1 += bf8_to_f32(u21) * w2; acc2 += bf8_to_f32(u22) * w2;
            acc0 += bf8_to_f32(u30) * w3; acc1 += bf8_to_f32(u31) * w3; acc2 += bf8_to_f32(u32) * w3;
        }
        for (; j < deg; ++j) {
            const unsigned int e = row[j];
            const float w = h16f((ushort)(e >> 16)) * dn;
            const ushort* p = A + (size_t)(e & 0xFFFFu) * 96 + grp * 24;
            acc0 += bf8_to_f32(*(const us8*)p) * w;
            acc1 += bf8_to_f32(*(const us8*)(p + 8)) * w;
            acc2 += bf8_to_f32(*(const us8*)(p + 16)) * w;
        }
        const float* bp = bias + grp * 24;
        us8 o0, o1, o2;
#pragma unroll
        for (int f = 0; f < 8; ++f) {
            o0[f] = bf16b(fmaxf(acc0[f] + bp[f],      0.0f));
            o1[f] = bf16b(fmaxf(acc1[f] + bp[8 + f],  0.0f));
            o2[f] = bf16b(fmaxf(acc2[f] + bp[16 + f], 0.0f));
        }
        ushort* sxp = sX + nl * 96 + grp * 24;
        *(us8*)sxp = o0; *(us8*)(sxp + 8) = o1; *(us8*)(sxp + 16) = o2;
    }
    __syncthreads();
    // garbage sX rows (OOB nodes) only affect their own output rows, which are not stored
    mfma_store(sX, sW, Y, rowbase);
}

// ---------------- final aggregate + fc (192 threads = 16 nodes x 12 chunks) ----------------
__global__ __launch_bounds__(192) void k_agg_fc(const ushort* __restrict__ A,
                                                const int* __restrict__ cnt,
                                                const unsigned int* __restrict__ csr,
                                                const float* __restrict__ bias,
                                                float* __restrict__ out4,
                                                const float* __restrict__ Wfc,
                                                const float* __restrict__ bfc) {
    __shared__ float sWfc[384];
    __shared__ float red[16][12][4];
    const int tid = threadIdx.x;
    for (int i = tid; i < 384; i += 192) sWfc[i] = Wfc[i];
    __syncthreads();
    const int g = tid / 12, c = tid % 12;
    const int n = blockIdx.x * 16 + g;

    const int deg = cnt[n];
    const float dn = rsqrtf((float)(deg + 1));
    us8 a0 = *(const us8*)(A + (size_t)n * 96 + c * 8);
    f32x8 acc = bf8_to_f32(a0) * (dn * dn);

    const unsigned int* row = csr + (size_t)n * SLOTS;
    int j = 0;
    for (; j + 4 <= deg; j += 4) {
        const uint4 q = *(const uint4*)(row + j);
        const us8 u0 = *(const us8*)(A + (size_t)(q.x & 0xFFFFu) * 96 + c * 8);
        const us8 u1 = *(const us8*)(A + (size_t)(q.y & 0xFFFFu) * 96 + c * 8);
        const us8 u2 = *(const us8*)(A + (size_t)(q.z & 0xFFFFu) * 96 + c * 8);
        const us8 u3 = *(const us8*)(A + (size_t)(q.w & 0xFFFFu) * 96 + c * 8);
        acc += bf8_to_f32(u0) * (h16f((ushort)(q.x >> 16)) * dn);
        acc += bf8_to_f32(u1) * (h16f((ushort)(q.y >> 16)) * dn);
        acc += bf8_to_f32(u2) * (h16f((ushort)(q.z >> 16)) * dn);
        acc += bf8_to_f32(u3) * (h16f((ushort)(q.w >> 16)) * dn);
    }
    for (; j < deg; ++j) {
        const unsigned int e = row[j];
        const float w = h16f((ushort)(e >> 16)) * dn;
        const us8 u = *(const us8*)(A + (size_t)(e & 0xFFFFu) * 96 + c * 8);
        acc += bf8_to_f32(u) * w;
    }
#pragma unroll
    for (int f = 0; f < 8; ++f) acc[f] = fmaxf(acc[f] + bias[c * 8 + f], 0.0f);

    float p0 = 0.f, p1 = 0.f, p2 = 0.f, p3 = 0.f;
#pragma unroll
    for (int f = 0; f < 8; ++f) {
        const float* wr = sWfc + (c * 8 + f) * 4;
        p0 += acc[f] * wr[0];
        p1 += acc[f] * wr[1];
        p2 += acc[f] * wr[2];
        p3 += acc[f] * wr[3];
    }
    red[g][c][0] = p0; red[g][c][1] = p1; red[g][c][2] = p2; red[g][c][3] = p3;
    __syncthreads();
    if (tid < 64) {
        const int gg = tid >> 2, jj = tid & 3;
        float s = bfc[jj];
#pragma unroll
        for (int cc = 0; cc < 12; ++cc) s += red[gg][cc][jj];
        out4[(size_t)(blockIdx.x * 16 + gg) * 4 + jj] = s;
    }
}

// ---------------- launch ----------------
extern "C" void kernel_launch(void* const* d_in, const int* in_sizes, int n_in,
                              void* d_out, int out_size, void* d_ws, size_t ws_size,
                              hipStream_t stream) {
    const float* x   = (const float*)d_in[0];
    const int*   ei  = (const int*)d_in[1];
    const int*   src = ei;
    const int*   dst = ei + N_EDGES;
    const float* W0  = (const float*)d_in[2];
    const float* b0  = (const float*)d_in[3];
    const float* W1  = (const float*)d_in[4];
    const float* b1  = (const float*)d_in[5];
    const float* W2  = (const float*)d_in[6];
    const float* b2  = (const float*)d_in[7];
    const float* Wfc = (const float*)d_in[8];
    const float* bfc = (const float*)d_in[9];
    float* out = (float*)d_out;

    // workspace layout (16 B-aligned blocks)
    char* w = (char*)d_ws;
    unsigned int* csr = (unsigned int*)w;  w += ((size_t)N_NODES * SLOTS * 4 + 15) & ~15ULL;
    int*    cnt  = (int*)w;                w += ((size_t)N_NODES * 4 + 15) & ~15ULL;
    ushort* rank = (ushort*)w;             w += ((size_t)N_EDGES * 2 + 15) & ~15ULL;
    ushort* Wt   = (ushort*)w;             w += ((size_t)3 * 9216 * 2 + 15) & ~15ULL;
    ushort* H    = (ushort*)w;             w += ((size_t)N_NODES * 96 * 2 + 15) & ~15ULL;
    ushort* G    = (ushort*)w;             // N_NODES * 96 bf16

    const int gAgg = N_NODES / 16;          // 3125, exact

    hipMemsetAsync(cnt, 0, (size_t)N_NODES * 4, stream);
    hipLaunchKernelGGL(k_count, dim3(GE + WBLK), dim3(256), 0, stream,
                       dst, cnt, rank, W0, W1, W2, Wt);
    // fill || gemm layer 1 (independent): one dispatch
    hipLaunchKernelGGL(k_fill_gemm1, dim3(GE + GMF), dim3(256), 0, stream,
                       src, dst, cnt, rank, csr, x, Wt, H);
    // agg1 + gemm2 fused (H -> G)
    hipLaunchKernelGGL(k_aggemm, dim3(GMF), dim3(256), 0, stream,
                       H, cnt, csr, b0, Wt + 9216, G);
    // agg2 + gemm3 fused (G -> H)
    hipLaunchKernelGGL(k_aggemm, dim3(GMF), dim3(256), 0, stream,
                       G, cnt, csr, b1, Wt + 2 * 9216, H);
    // agg3 + fc (H -> out)
    hipLaunchKernelGGL(k_agg_fc, dim3(gAgg), dim3(192), 0, stream,
                       H, cnt, csr, b2, out, Wfc, bfc);
}